// Round 4
// baseline (2494.017 us; speedup 1.0000x reference)
//
#include <hip/hip_runtime.h>
#include <math.h>

typedef unsigned int u32;
typedef unsigned short u16;
typedef short s16x8 __attribute__((ext_vector_type(8)));
typedef float f32x4 __attribute__((ext_vector_type(4)));
typedef u16 u16x4 __attribute__((ext_vector_type(4)));
typedef u16 u16x8 __attribute__((ext_vector_type(8)));

#define B_  16
#define S_  2048
#define D_  1024
#define H_  256
#define SD_ 14
#define C_  6
#define G_  3
#define E_  18

static __device__ __forceinline__ u16 f2bf(float f) {
  u32 x = __builtin_bit_cast(u32, f);
  return (u16)((x + 0x7fffu + ((x >> 16) & 1u)) >> 16);
}

// ---------------- K3: convert features f32->bf16 + column-mean pooling ----------------
__global__ __launch_bounds__(256) void k_convpool(const float* __restrict__ F,
                                                  u16* __restrict__ Fbf,
                                                  float* __restrict__ fsum) {
  const int bb = blockIdx.x >> 5;   // batch 0..15
  const int sc = blockIdx.x & 31;   // 64-row chunk 0..31
  const int t  = threadIdx.x;       // 0..255, each owns 4 columns
  const size_t base = (size_t)(bb * S_ + sc * 64) * D_ + t * 4;
  float s0 = 0.f, s1 = 0.f, s2 = 0.f, s3 = 0.f;
  for (int i = 0; i < 64; ++i) {
    const f32x4 v = *(const f32x4*)(F + base + (size_t)i * D_);
    s0 += v[0]; s1 += v[1]; s2 += v[2]; s3 += v[3];
    u16x4 h;
    h[0] = f2bf(v[0]); h[1] = f2bf(v[1]); h[2] = f2bf(v[2]); h[3] = f2bf(v[3]);
    *(u16x4*)(Fbf + base + (size_t)i * D_) = h;
  }
  const int c = t * 4;
  atomicAdd(&fsum[bb * D_ + c + 0], s0);
  atomicAdd(&fsum[bb * D_ + c + 1], s1);
  atomicAdd(&fsum[bb * D_ + c + 2], s2);
  atomicAdd(&fsum[bb * D_ + c + 3], s3);
}

// ---------------- K3b: pooling only (lean path) ----------------
__global__ __launch_bounds__(256) void k_poolF(const float* __restrict__ F,
                                               float* __restrict__ fsum) {
  const int bb = blockIdx.x >> 5;
  const int sc = blockIdx.x & 31;
  const int t  = threadIdx.x;
  const size_t base = (size_t)(bb * S_ + sc * 64) * D_ + t * 4;
  float s0 = 0.f, s1 = 0.f, s2 = 0.f, s3 = 0.f;
  for (int i = 0; i < 64; ++i) {
    const f32x4 v = *(const f32x4*)(F + base + (size_t)i * D_);
    s0 += v[0]; s1 += v[1]; s2 += v[2]; s3 += v[3];
  }
  const int c = t * 4;
  atomicAdd(&fsum[bb * D_ + c + 0], s0);
  atomicAdd(&fsum[bb * D_ + c + 1], s1);
  atomicAdd(&fsum[bb * D_ + c + 2], s2);
  atomicAdd(&fsum[bb * D_ + c + 3], s3);
}

// ---------------- K1: x_raw column-mean pooling ----------------
__global__ __launch_bounds__(256) void k_xpool(const float* __restrict__ X,
                                               float* __restrict__ xsum) {
  const int b = blockIdx.x;
  const int t = threadIdx.x;
  float ls[SD_];
  #pragma unroll
  for (int c = 0; c < SD_; ++c) ls[c] = 0.f;
  for (int s = t; s < S_; s += 256) {
    const float* row = X + (size_t)(b * S_ + s) * SD_;
    #pragma unroll
    for (int c = 0; c < SD_; ++c) ls[c] += row[c];
  }
  #pragma unroll
  for (int c = 0; c < SD_; ++c) atomicAdd(&xsum[b * SD_ + c], ls[c]);
}

// ---------------- K2: routers + flat weights + expert loads + lb + bias term ----------------
__global__ __launch_bounds__(256) void k_router(const float* __restrict__ fsum,
                                                const float* __restrict__ xsum,
                                                const float* __restrict__ cond_w,
                                                const float* __restrict__ cond_b,
                                                const float* __restrict__ stage_w,
                                                const float* __restrict__ stage_b,
                                                const float* __restrict__ up_b,
                                                float* __restrict__ flatw,
                                                float* __restrict__ biasws,
                                                float* __restrict__ out_tail) {
  __shared__ float s_cl[B_][C_], s_sl[B_][G_];
  __shared__ float s_cw[B_][C_], s_sw[B_][G_];
  __shared__ float s_fw[B_][E_], s_ld[E_];
  const int t = threadIdx.x;
  if (t < B_ * C_) {
    const int b = t / C_, c = t % C_;
    float a = cond_b[c];
    for (int d = 0; d < D_; ++d) a += (fsum[b * D_ + d] * (1.f / S_)) * cond_w[d * C_ + c];
    s_cl[b][c] = a;
  }
  if (t < B_ * G_) {
    const int b = t / G_, g = t % G_;
    float a = stage_b[g];
    for (int sd = 0; sd < SD_; ++sd) a += (xsum[b * SD_ + sd] * (1.f / S_)) * stage_w[sd * G_ + g];
    s_sl[b][g] = a;
  }
  __syncthreads();
  if (t < B_) {
    float m = s_cl[t][0];
    for (int c = 1; c < C_; ++c) m = fmaxf(m, s_cl[t][c]);
    float den = 0.f, ex[C_];
    for (int c = 0; c < C_; ++c) { ex[c] = expf(s_cl[t][c] - m); den += ex[c]; }
    for (int c = 0; c < C_; ++c) s_cw[t][c] = ex[c] / den;
    float m2 = s_sl[t][0];
    for (int g = 1; g < G_; ++g) m2 = fmaxf(m2, s_sl[t][g]);
    float den2 = 0.f, ex2[G_];
    for (int g = 0; g < G_; ++g) { ex2[g] = expf(s_sl[t][g] - m2); den2 += ex2[g]; }
    for (int g = 0; g < G_; ++g) s_sw[t][g] = ex2[g] / den2;
    for (int c = 0; c < C_; ++c)
      for (int g = 0; g < G_; ++g) s_fw[t][c * G_ + g] = s_cw[t][c] * s_sw[t][g];
  }
  __syncthreads();
  if (t < B_ * C_) out_tail[t] = s_cw[t / C_][t % C_];
  if (t < B_ * G_) out_tail[B_ * C_ + t] = s_sw[t / G_][t % G_];
  // B_*E_ = 288 > 256 threads: strided loop (round-1 bug fix)
  for (int i = t; i < B_ * E_; i += 256) flatw[i] = s_fw[i / E_][i % E_];
  if (t < E_) {
    float a = 0.f;
    for (int b = 0; b < B_; ++b) a += s_fw[b][t];
    s_ld[t] = a / (float)B_;
    out_tail[B_ * C_ + B_ * G_ + t] = s_ld[t];
  }
  __syncthreads();
  if (t == 0) {
    float a = 0.f;
    for (int e = 0; e < E_; ++e) a += s_ld[e] * s_ld[e];
    out_tail[B_ * C_ + B_ * G_ + E_] = (float)E_ * a * 0.01f;
  }
  for (int i = t; i < B_ * D_; i += 256) {
    const int b = i >> 10, d = i & 1023;
    float a = 0.f;
    #pragma unroll
    for (int e = 0; e < E_; ++e) a += s_fw[b][e] * up_b[e * D_ + d];
    biasws[i] = a;
  }
}

// ---------------- K4: [E][Rr][Cc] f32 -> [E][Cc][Rr] bf16 transpose ----------------
__global__ __launch_bounds__(256) void k_transpose(const float* __restrict__ src,
                                                   u16* __restrict__ dst, int Rr, int Cc) {
  const int tiles_c = Cc >> 6, tiles_r = Rr >> 6;
  const int id = blockIdx.x;
  const int e = id / (tiles_r * tiles_c);
  const int rem = id % (tiles_r * tiles_c);
  const int r0 = (rem / tiles_c) << 6, c0 = (rem % tiles_c) << 6;
  __shared__ float tile[64][65];
  const int t = threadIdx.x;
  const float* sp = src + (size_t)e * Rr * Cc;
  #pragma unroll
  for (int i = 0; i < 4; ++i) {
    const int lin = i * 1024 + t * 4;
    const int r = lin >> 6, c = lin & 63;
    const f32x4 v = *(const f32x4*)(sp + (size_t)(r0 + r) * Cc + c0 + c);
    tile[r][c] = v[0]; tile[r][c + 1] = v[1]; tile[r][c + 2] = v[2]; tile[r][c + 3] = v[3];
  }
  __syncthreads();
  u16* dp = dst + (size_t)e * Rr * Cc;
  #pragma unroll
  for (int i = 0; i < 4; ++i) {
    const int lin = i * 1024 + t * 4;
    const int cr = lin >> 6, rc = lin & 63;
    u16x4 h;
    h[0] = f2bf(tile[rc + 0][cr]);
    h[1] = f2bf(tile[rc + 1][cr]);
    h[2] = f2bf(tile[rc + 2][cr]);
    h[3] = f2bf(tile[rc + 3][cr]);
    *(u16x4*)(dp + (size_t)(c0 + cr) * Rr + r0 + rc) = h;
  }
}

#define MFMA_BF16 __builtin_amdgcn_mfma_f32_16x16x32_bf16

// ---------------- K5: fused MoE main kernel (v4: BM=32) ----------------
// 32 rows x full D=1024 per WG, 1024 WGs. 8 waves. acc = 64 AGPR/lane (half of
// round 2/3) -> ~190 VGPRs free for real prefetch without spilling (round-3
// lesson: occupancy x registers is conserved; BM=64's 128-AGPR acc left zero
// headroom and every prefetch reg spilled to scratch).
// Hb double-buffered -> ONE barrier per expert.
template<int LEAN>
__global__ __launch_bounds__(512, 2) void k_moe(const u16* __restrict__ Fbf,
                                                const float* __restrict__ Ff32,
                                                const u16* __restrict__ dwT,   // [E][H][D] bf16
                                                const u16* __restrict__ uwT,   // [E][D][H] bf16
                                                const float* __restrict__ down_b,
                                                const float* __restrict__ flatw,
                                                const float* __restrict__ biasws,
                                                float* __restrict__ out) {
  __shared__ u16 Fb[32 * 1024];     // 64 KiB, row stride 2048B, XOR-swizzled 16B slots
  __shared__ u16 Hb[2][32 * 256];   // 2 x 16 KiB, row stride 512B, XOR-swizzled

  const int tile = blockIdx.x;
  const int r0 = tile * 32;
  const int b = r0 >> 11;
  const int t = threadIdx.x;
  const int w = t >> 6;
  const int l = t & 63;
  const int l15 = l & 15;
  const int lhi = l >> 4;
  const int sw7 = (l & 7) << 4;

  // ---- stage F tile (once, reused by all 18 experts) ----
  #pragma unroll
  for (int i = 0; i < 8; ++i) {
    const int slot = i * 512 + t;   // 16B slots, 4096 total
    const int row = slot >> 7;      // 0..31
    const int isl = slot & 127;
    char* dst = (char*)Fb + row * 2048 + ((isl * 16) ^ ((row & 7) << 4));
    if constexpr (!LEAN) {
      *(u16x8*)dst = *(const u16x8*)(Fbf + (size_t)(r0 + row) * D_ + isl * 8);
    } else {
      const float* src = Ff32 + (size_t)(r0 + row) * D_ + isl * 8;
      const f32x4 v0 = *(const f32x4*)src;
      const f32x4 v1 = *(const f32x4*)(src + 4);
      u16x8 h;
      h[0] = f2bf(v0[0]); h[1] = f2bf(v0[1]); h[2] = f2bf(v0[2]); h[3] = f2bf(v0[3]);
      h[4] = f2bf(v1[0]); h[5] = f2bf(v1[1]); h[6] = f2bf(v1[2]); h[7] = f2bf(v1[3]);
      *(u16x8*)dst = h;
    }
  }

  // down-B pointer: wave's h-rows w*32+l15 and +16 of dwT[e], k-offset lhi*8
  const u16* bptr = dwT + (size_t)(w * 32 + l15) * D_ + lhi * 8;
  // preload expert-0 down-B frags, depth 8 (rolling; overlaps staging+barrier)
  s16x8 pb0[8], pb1[8];
  #pragma unroll
  for (int p = 0; p < 8; ++p) {
    pb0[p] = *(const s16x8*)(bptr + (size_t)p * 32);
    pb1[p] = *(const s16x8*)(bptr + (size_t)16 * D_ + p * 32);
  }

  f32x4 acc[2][8];
  #pragma unroll
  for (int i = 0; i < 2; ++i)
    #pragma unroll
    for (int j = 0; j < 8; ++j)
      acc[i][j] = f32x4{0.f, 0.f, 0.f, 0.f};

  __syncthreads();

  const float* fwb = flatw + b * E_;

  #pragma unroll 1
  for (int e = 0; e < E_; ++e) {
    char* hb = (char*)Hb[e & 1];
    // ---- DOWN: h[32 x 32cols/wave] = F(32x1024) @ dw[e] ----
    f32x4 hacc[2][2];
    #pragma unroll
    for (int fr = 0; fr < 2; ++fr) {
      hacc[fr][0] = f32x4{0.f, 0.f, 0.f, 0.f};
      hacc[fr][1] = f32x4{0.f, 0.f, 0.f, 0.f};
    }
    s16x8 areg[2][2];
    #pragma unroll
    for (int fr = 0; fr < 2; ++fr)
      areg[0][fr] = *(const s16x8*)((const char*)Fb + (l15 + fr * 16) * 2048 + ((lhi * 16) ^ sw7));
    #pragma unroll
    for (int kk = 0; kk < 32; ++kk) {
      const int cur = kk & 1, nxt = cur ^ 1;
      if (kk < 31) {
        const int kb = (kk + 1) * 64;
        #pragma unroll
        for (int fr = 0; fr < 2; ++fr)
          areg[nxt][fr] = *(const s16x8*)((const char*)Fb + (l15 + fr * 16) * 2048 + ((kb + lhi * 16) ^ sw7));
      }
      const s16x8 b0 = pb0[kk & 7];
      const s16x8 b1 = pb1[kk & 7];
      if (kk < 24) {
        pb0[kk & 7] = *(const s16x8*)(bptr + (size_t)(kk + 8) * 32);
        pb1[kk & 7] = *(const s16x8*)(bptr + (size_t)16 * D_ + (kk + 8) * 32);
      }
      #pragma unroll
      for (int fr = 0; fr < 2; ++fr) {
        hacc[fr][0] = MFMA_BF16(areg[cur][fr], b0, hacc[fr][0], 0, 0, 0);
        hacc[fr][1] = MFMA_BF16(areg[cur][fr], b1, hacc[fr][1], 0, 0, 0);
      }
    }

    // ---- gelu + scale -> Hb[e&1]; meanwhile issue up-B(ks=0) + next-expert down-B ----
    const u16* uwe = uwT + (size_t)e * (D_ * H_) + (size_t)(w * 128 + l15) * H_ + lhi * 8;
    s16x8 ub[2][8];
    #pragma unroll
    for (int fc = 0; fc < 8; ++fc)
      ub[0][fc] = *(const s16x8*)(uwe + (size_t)(fc * 16) * H_);

    const float wbe = fwb[e];
    #pragma unroll
    for (int fc = 0; fc < 2; ++fc) {
      const int hc = w * 32 + fc * 16 + l15;
      const float dbv = down_b[e * H_ + hc];
      #pragma unroll
      for (int fr = 0; fr < 2; ++fr) {
        #pragma unroll
        for (int i = 0; i < 4; ++i) {
          const int row = fr * 16 + lhi * 4 + i;
          const float x = hacc[fr][fc][i] + dbv;
          const float g = 0.5f * x * (1.f + erff(x * 0.70710678f));
          *(u16*)(hb + row * 512 + ((hc * 2) ^ ((row & 7) << 4))) = f2bf(g * wbe);
        }
      }
    }

    bptr += (size_t)H_ * D_;   // next expert's down weights
    if (e + 1 < E_) {
      #pragma unroll
      for (int p = 0; p < 8; ++p) {
        pb0[p] = *(const s16x8*)(bptr + (size_t)p * 32);
        pb1[p] = *(const s16x8*)(bptr + (size_t)16 * D_ + p * 32);
      }
    }
    // Single barrier per expert: makes this expert's Hb[e&1] visible for the
    // up phase. up(e) [reads Hb[e&1]] races only with gelu(e+1) [writes
    // Hb[(e+1)&1]] - different buffer; gelu(e+2) is fenced by barrier(e+1).
    __syncthreads();

    // ---- UP: acc[32 x 128cols/wave] += Hb(32x256) @ uw[e] ----
    s16x8 ua[2][2];
    #pragma unroll
    for (int fr = 0; fr < 2; ++fr)
      ua[0][fr] = *(const s16x8*)(hb + (l15 + fr * 16) * 512 + ((lhi * 16) ^ sw7));
    #pragma unroll
    for (int ks = 0; ks < 8; ++ks) {
      const int cur = ks & 1, nxt = cur ^ 1;
      if (ks < 7) {
        const int kb = (ks + 1) * 64;
        #pragma unroll
        for (int fr = 0; fr < 2; ++fr)
          ua[nxt][fr] = *(const s16x8*)(hb + (l15 + fr * 16) * 512 + ((kb + lhi * 16) ^ sw7));
        #pragma unroll
        for (int fc = 0; fc < 8; ++fc)
          ub[nxt][fc] = *(const s16x8*)(uwe + (size_t)(fc * 16) * H_ + (ks + 1) * 32);
      }
      #pragma unroll
      for (int fc = 0; fc < 8; ++fc) {
        #pragma unroll
        for (int fr = 0; fr < 2; ++fr)
          acc[fr][fc] = MFMA_BF16(ua[cur][fr], ub[cur][fc], acc[fr][fc], 0, 0, 0);
      }
    }
  }

  // ---- epilogue: residual (f32 features) + bias term + store ----
  const float* bias = biasws + b * D_;
  #pragma unroll
  for (int fc = 0; fc < 8; ++fc) {
    const int col = w * 128 + fc * 16 + l15;
    const float bv = bias[col];
    #pragma unroll
    for (int fr = 0; fr < 2; ++fr) {
      #pragma unroll
      for (int i = 0; i < 4; ++i) {
        const int row = fr * 16 + lhi * 4 + i;
        const size_t idx = (size_t)(r0 + row) * D_ + col;
        out[idx] = acc[fr][fc][i] + Ff32[idx] + bv;
      }
    }
  }
}

extern "C" void kernel_launch(void* const* d_in, const int* in_sizes, int n_in,
                              void* d_out, int out_size, void* d_ws, size_t ws_size,
                              hipStream_t stream) {
  const float* F  = (const float*)d_in[0];
  const float* X  = (const float*)d_in[1];
  const float* dw = (const float*)d_in[2];
  const float* db = (const float*)d_in[3];
  const float* uw = (const float*)d_in[4];
  const float* ub = (const float*)d_in[5];
  const float* cw = (const float*)d_in[6];
  const float* cb = (const float*)d_in[7];
  const float* sw = (const float*)d_in[8];
  const float* sb = (const float*)d_in[9];
  float* out = (float*)d_out;

  char* ws = (char*)d_ws;
  float* fsum  = (float*)ws;                 // B*D
  float* xsum  = fsum + B_ * D_;             // B*SD
  float* flatw = xsum + B_ * SD_;            // B*E
  float* biasws = flatw + B_ * E_;           // B*D
  size_t off = (size_t)(B_ * D_ + B_ * SD_ + B_ * E_ + B_ * D_) * 4;
  off = (off + 255) & ~(size_t)255;
  u16* dwT = (u16*)(ws + off); off += (size_t)E_ * H_ * D_ * 2;
  u16* uwT = (u16*)(ws + off); off += (size_t)E_ * D_ * H_ * 2;
  const size_t need_lean = off;
  u16* Fbf = (u16*)(ws + off); off += (size_t)B_ * S_ * D_ * 2;
  const size_t need_full = off;

  if (ws_size < need_lean) return;
  const bool lean = ws_size < need_full;

  hipMemsetAsync(d_ws, 0, (size_t)(B_ * D_ + B_ * SD_) * sizeof(float), stream);
  k_transpose<<<E_ * 16 * 4, 256, 0, stream>>>(dw, dwT, D_, H_);  // [E][D][H] -> [E][H][D]
  k_transpose<<<E_ * 4 * 16, 256, 0, stream>>>(uw, uwT, H_, D_);  // [E][H][D] -> [E][D][H]
  if (!lean) {
    k_convpool<<<512, 256, 0, stream>>>(F, Fbf, fsum);
  } else {
    k_poolF<<<512, 256, 0, stream>>>(F, fsum);
  }
  k_xpool<<<B_, 256, 0, stream>>>(X, xsum);
  k_router<<<1, 256, 0, stream>>>(fsum, xsum, cw, cb, sw, sb, ub, flatw, biasws,
                                  out + (size_t)B_ * S_ * D_);
  if (!lean) {
    k_moe<0><<<1024, 512, 0, stream>>>(Fbf, F, dwT, uwT, db, flatw, biasws, out);
  } else {
    k_moe<1><<<1024, 512, 0, stream>>>(nullptr, F, dwT, uwT, db, flatw, biasws, out);
  }
}

// Round 5
// 1274.626 us; speedup vs baseline: 1.9567x; 1.9567x over previous
//
#include <hip/hip_runtime.h>
#include <math.h>

typedef unsigned int u32;
typedef unsigned short u16;
typedef short s16x8 __attribute__((ext_vector_type(8)));
typedef float f32x4 __attribute__((ext_vector_type(4)));
typedef u16 u16x4 __attribute__((ext_vector_type(4)));
typedef u16 u16x8 __attribute__((ext_vector_type(8)));

#define B_  16
#define S_  2048
#define D_  1024
#define H_  256
#define SD_ 14
#define C_  6
#define G_  3
#define E_  18

static __device__ __forceinline__ u16 f2bf(float f) {
  u32 x = __builtin_bit_cast(u32, f);
  return (u16)((x + 0x7fffu + ((x >> 16) & 1u)) >> 16);
}

// ---------------- K3: convert features f32->bf16 + column-mean pooling ----------------
__global__ __launch_bounds__(256) void k_convpool(const float* __restrict__ F,
                                                  u16* __restrict__ Fbf,
                                                  float* __restrict__ fsum) {
  const int bb = blockIdx.x >> 5;
  const int sc = blockIdx.x & 31;
  const int t  = threadIdx.x;
  const size_t base = (size_t)(bb * S_ + sc * 64) * D_ + t * 4;
  float s0 = 0.f, s1 = 0.f, s2 = 0.f, s3 = 0.f;
  for (int i = 0; i < 64; ++i) {
    const f32x4 v = *(const f32x4*)(F + base + (size_t)i * D_);
    s0 += v[0]; s1 += v[1]; s2 += v[2]; s3 += v[3];
    u16x4 h;
    h[0] = f2bf(v[0]); h[1] = f2bf(v[1]); h[2] = f2bf(v[2]); h[3] = f2bf(v[3]);
    *(u16x4*)(Fbf + base + (size_t)i * D_) = h;
  }
  const int c = t * 4;
  atomicAdd(&fsum[bb * D_ + c + 0], s0);
  atomicAdd(&fsum[bb * D_ + c + 1], s1);
  atomicAdd(&fsum[bb * D_ + c + 2], s2);
  atomicAdd(&fsum[bb * D_ + c + 3], s3);
}

// ---------------- K3b: pooling only (lean path) ----------------
__global__ __launch_bounds__(256) void k_poolF(const float* __restrict__ F,
                                               float* __restrict__ fsum) {
  const int bb = blockIdx.x >> 5;
  const int sc = blockIdx.x & 31;
  const int t  = threadIdx.x;
  const size_t base = (size_t)(bb * S_ + sc * 64) * D_ + t * 4;
  float s0 = 0.f, s1 = 0.f, s2 = 0.f, s3 = 0.f;
  for (int i = 0; i < 64; ++i) {
    const f32x4 v = *(const f32x4*)(F + base + (size_t)i * D_);
    s0 += v[0]; s1 += v[1]; s2 += v[2]; s3 += v[3];
  }
  const int c = t * 4;
  atomicAdd(&fsum[bb * D_ + c + 0], s0);
  atomicAdd(&fsum[bb * D_ + c + 1], s1);
  atomicAdd(&fsum[bb * D_ + c + 2], s2);
  atomicAdd(&fsum[bb * D_ + c + 3], s3);
}

// ---------------- K1: x_raw column-mean pooling ----------------
__global__ __launch_bounds__(256) void k_xpool(const float* __restrict__ X,
                                               float* __restrict__ xsum) {
  const int b = blockIdx.x;
  const int t = threadIdx.x;
  float ls[SD_];
  #pragma unroll
  for (int c = 0; c < SD_; ++c) ls[c] = 0.f;
  for (int s = t; s < S_; s += 256) {
    const float* row = X + (size_t)(b * S_ + s) * SD_;
    #pragma unroll
    for (int c = 0; c < SD_; ++c) ls[c] += row[c];
  }
  #pragma unroll
  for (int c = 0; c < SD_; ++c) atomicAdd(&xsum[b * SD_ + c], ls[c]);
}

// ---------------- K2: routers + flat weights + expert loads + lb + bias term ----------------
__global__ __launch_bounds__(256) void k_router(const float* __restrict__ fsum,
                                                const float* __restrict__ xsum,
                                                const float* __restrict__ cond_w,
                                                const float* __restrict__ cond_b,
                                                const float* __restrict__ stage_w,
                                                const float* __restrict__ stage_b,
                                                const float* __restrict__ up_b,
                                                float* __restrict__ flatw,
                                                float* __restrict__ biasws,
                                                float* __restrict__ out_tail) {
  __shared__ float s_cl[B_][C_], s_sl[B_][G_];
  __shared__ float s_cw[B_][C_], s_sw[B_][G_];
  __shared__ float s_fw[B_][E_], s_ld[E_];
  const int t = threadIdx.x;
  if (t < B_ * C_) {
    const int b = t / C_, c = t % C_;
    float a = cond_b[c];
    for (int d = 0; d < D_; ++d) a += (fsum[b * D_ + d] * (1.f / S_)) * cond_w[d * C_ + c];
    s_cl[b][c] = a;
  }
  if (t < B_ * G_) {
    const int b = t / G_, g = t % G_;
    float a = stage_b[g];
    for (int sd = 0; sd < SD_; ++sd) a += (xsum[b * SD_ + sd] * (1.f / S_)) * stage_w[sd * G_ + g];
    s_sl[b][g] = a;
  }
  __syncthreads();
  if (t < B_) {
    float m = s_cl[t][0];
    for (int c = 1; c < C_; ++c) m = fmaxf(m, s_cl[t][c]);
    float den = 0.f, ex[C_];
    for (int c = 0; c < C_; ++c) { ex[c] = expf(s_cl[t][c] - m); den += ex[c]; }
    for (int c = 0; c < C_; ++c) s_cw[t][c] = ex[c] / den;
    float m2 = s_sl[t][0];
    for (int g = 1; g < G_; ++g) m2 = fmaxf(m2, s_sl[t][g]);
    float den2 = 0.f, ex2[G_];
    for (int g = 0; g < G_; ++g) { ex2[g] = expf(s_sl[t][g] - m2); den2 += ex2[g]; }
    for (int g = 0; g < G_; ++g) s_sw[t][g] = ex2[g] / den2;
    for (int c = 0; c < C_; ++c)
      for (int g = 0; g < G_; ++g) s_fw[t][c * G_ + g] = s_cw[t][c] * s_sw[t][g];
  }
  __syncthreads();
  if (t < B_ * C_) out_tail[t] = s_cw[t / C_][t % C_];
  if (t < B_ * G_) out_tail[B_ * C_ + t] = s_sw[t / G_][t % G_];
  for (int i = t; i < B_ * E_; i += 256) flatw[i] = s_fw[i / E_][i % E_];
  if (t < E_) {
    float a = 0.f;
    for (int b = 0; b < B_; ++b) a += s_fw[b][t];
    s_ld[t] = a / (float)B_;
    out_tail[B_ * C_ + B_ * G_ + t] = s_ld[t];
  }
  __syncthreads();
  if (t == 0) {
    float a = 0.f;
    for (int e = 0; e < E_; ++e) a += s_ld[e] * s_ld[e];
    out_tail[B_ * C_ + B_ * G_ + E_] = (float)E_ * a * 0.01f;
  }
  for (int i = t; i < B_ * D_; i += 256) {
    const int b = i >> 10, d = i & 1023;
    float a = 0.f;
    #pragma unroll
    for (int e = 0; e < E_; ++e) a += s_fw[b][e] * up_b[e * D_ + d];
    biasws[i] = a;
  }
}

// ---------------- K4: fragmentizer ----------------
// src: [E][K][N] f32 (K = contraction dim, N = output cols).
// dst: frag-linear bf16 [e][kb=K/32][cb=N/16][lane=64][8]:
//   dst value = src[e][kb*32 + (lane>>4)*8 + j][cb*16 + (lane&15)]
// so a wave's B-frag load for (kb,cb) is ONE coalesced 1KB read (lane l -> +l*16B).
__global__ __launch_bounds__(256) void k_frag(const float* __restrict__ src,
                                              u16* __restrict__ dst, int K, int N) {
  const int kgrp = K >> 7;           // groups of 128 k-rows
  const int ncb = N >> 4;
  const int bid = blockIdx.x;
  const int kbg = bid % kgrp;
  const int cb  = (bid / kgrp) % ncb;
  const int e   = bid / (kgrp * ncb);
  __shared__ float tile[128][17];
  const int t = threadIdx.x;
  // stage 128 k-rows x 16 cols, coalesced 64B per 16-lane group
  #pragma unroll
  for (int it = 0; it < 8; ++it) {
    const int i = it * 256 + t;
    const int row = i >> 4, col = i & 15;
    tile[row][col] = src[((size_t)e * K + kbg * 128 + row) * N + cb * 16 + col];
  }
  __syncthreads();
  const int lane = t & 63, kbq = t >> 6;       // 4 kb-chunks of 32
  const int l15 = lane & 15, lhi = lane >> 4;
  const int kb = kbg * 4 + kbq;
  u16x8 h;
  #pragma unroll
  for (int j = 0; j < 8; ++j) h[j] = f2bf(tile[kbq * 32 + lhi * 8 + j][l15]);
  *(u16x8*)(dst + ((((size_t)e * (K >> 5) + kb) * ncb + cb) * 64 + lane) * 8) = h;
}

#define MFMA_BF16 __builtin_amdgcn_mfma_f32_16x16x32_bf16

// fast gelu: x * p/(p+1) with p = exp2(2*log2(e)*0.79788456*(x + 0.044715 x^3))
static __device__ __forceinline__ float gelu_f(float x) {
  float y2 = 2.302208f * x * (1.f + 0.044715f * x * x);  // 2*1.442695*0.7978846
  y2 = fminf(fmaxf(y2, -30.f), 30.f);
  const float p = __builtin_exp2f(y2);
  return x * p / (p + 1.f);
}

// ---------------- K5: fused MoE main kernel (v5) ----------------
// BM=32 rows, 512 thr / 8 waves. Wave w: down h-cols [w*32,+32) (cb=2w,2w+1),
// up out-cols [w*128,+128) (cb'=w*8+fc). acc=64 regs; prefetch ~120 regs;
// total ~230 < 256-reg cap at 2 waves/SIMD (round-3/4 lesson).
// Weights read via frag-linear layout: every load = 1KB coalesced per wave.
// Hb double-buffered -> 1 barrier/expert.
template<int LEAN>
__global__ __launch_bounds__(512, 2) void k_moe(const u16* __restrict__ Fbf,
                                                const float* __restrict__ Ff32,
                                                const u16* __restrict__ dwF,   // [e][32][16][64][8]
                                                const u16* __restrict__ uwF,   // [e][8][64][64][8]
                                                const float* __restrict__ down_b,
                                                const float* __restrict__ flatw,
                                                const float* __restrict__ biasws,
                                                float* __restrict__ out) {
  __shared__ u16 Fb[32 * 1024];     // 64 KiB, row stride 2048B, XOR-swizzled 16B slots
  __shared__ u16 Hb[2][32 * 256];   // 2 x 16 KiB

  const int tile = blockIdx.x;
  const int r0 = tile * 32;
  const int b = r0 >> 11;
  const int t = threadIdx.x;
  const int w = t >> 6;
  const int l = t & 63;
  const int l15 = l & 15;
  const int lhi = l >> 4;
  const int sw7 = (l & 7) << 4;

  // ---- stage F tile ----
  #pragma unroll
  for (int i = 0; i < 8; ++i) {
    const int slot = i * 512 + t;
    const int row = slot >> 7;
    const int isl = slot & 127;
    char* dst = (char*)Fb + row * 2048 + ((isl * 16) ^ ((row & 7) << 4));
    if constexpr (!LEAN) {
      *(u16x8*)dst = *(const u16x8*)(Fbf + (size_t)(r0 + row) * D_ + isl * 8);
    } else {
      const float* src = Ff32 + (size_t)(r0 + row) * D_ + isl * 8;
      const f32x4 v0 = *(const f32x4*)src;
      const f32x4 v1 = *(const f32x4*)(src + 4);
      u16x8 h;
      h[0] = f2bf(v0[0]); h[1] = f2bf(v0[1]); h[2] = f2bf(v0[2]); h[3] = f2bf(v0[3]);
      h[4] = f2bf(v1[0]); h[5] = f2bf(v1[1]); h[6] = f2bf(v1[2]); h[7] = f2bf(v1[3]);
      *(u16x8*)dst = h;
    }
  }

  // down-B frag base for this wave/lane: [e][kk][cb][lane][8], wave covers cb=2w,2w+1
  const u16* dB = dwF + ((size_t)(2 * w) * 64 + l) * 8;   // + (e*32+kk)*16*512
  const u16* uB = uwF + ((size_t)(8 * w) * 64 + l) * 8;   // + (e*8+ks)*64*512, frag fc: +fc*512

  // preload expert-0 down-B, depth 4 (kk=0..3), 2 frags each
  s16x8 pb[4][2];
  #pragma unroll
  for (int p = 0; p < 4; ++p) {
    pb[p][0] = *(const s16x8*)(dB + (size_t)p * 16 * 512);
    pb[p][1] = *(const s16x8*)(dB + (size_t)p * 16 * 512 + 512);
  }

  f32x4 acc[2][8];
  #pragma unroll
  for (int i = 0; i < 2; ++i)
    #pragma unroll
    for (int j = 0; j < 8; ++j)
      acc[i][j] = f32x4{0.f, 0.f, 0.f, 0.f};

  __syncthreads();

  const float* fwb = flatw + b * E_;

  #pragma unroll 1
  for (int e = 0; e < E_; ++e) {
    char* hb = (char*)Hb[e & 1];
    const u16* dBe = dB + (size_t)e * 32 * 16 * 512;
    // ---- DOWN: h[32 x 32cols/wave] ----
    f32x4 hacc[2][2];
    #pragma unroll
    for (int fr = 0; fr < 2; ++fr) {
      hacc[fr][0] = f32x4{0.f, 0.f, 0.f, 0.f};
      hacc[fr][1] = f32x4{0.f, 0.f, 0.f, 0.f};
    }
    s16x8 areg[2][2];
    #pragma unroll
    for (int fr = 0; fr < 2; ++fr)
      areg[0][fr] = *(const s16x8*)((const char*)Fb + (l15 + fr * 16) * 2048 + ((lhi * 16) ^ sw7));
    #pragma unroll
    for (int kk = 0; kk < 32; ++kk) {
      const int cur = kk & 1, nxt = cur ^ 1;
      if (kk < 31) {
        const int kb = (kk + 1) * 64;
        #pragma unroll
        for (int fr = 0; fr < 2; ++fr)
          areg[nxt][fr] = *(const s16x8*)((const char*)Fb + (l15 + fr * 16) * 2048 + ((kb + lhi * 16) ^ sw7));
      }
      const s16x8 b0 = pb[kk & 3][0];
      const s16x8 b1 = pb[kk & 3][1];
      if (kk < 28) {
        pb[kk & 3][0] = *(const s16x8*)(dBe + (size_t)(kk + 4) * 16 * 512);
        pb[kk & 3][1] = *(const s16x8*)(dBe + (size_t)(kk + 4) * 16 * 512 + 512);
      }
      #pragma unroll
      for (int fr = 0; fr < 2; ++fr) {
        hacc[fr][0] = MFMA_BF16(areg[cur][fr], b0, hacc[fr][0], 0, 0, 0);
        hacc[fr][1] = MFMA_BF16(areg[cur][fr], b1, hacc[fr][1], 0, 0, 0);
      }
    }

    // ---- issue up-B(ks=0) loads, then gelu -> Hb[e&1], then next-expert pb ----
    const u16* uBe = uB + (size_t)e * 8 * 64 * 512;
    s16x8 ub[2][8];
    #pragma unroll
    for (int fc = 0; fc < 8; ++fc)
      ub[0][fc] = *(const s16x8*)(uBe + (size_t)fc * 512);

    const float wbe = fwb[e];
    #pragma unroll
    for (int fc = 0; fc < 2; ++fc) {
      const int hc = w * 32 + fc * 16 + l15;
      const float dbv = down_b[e * H_ + hc];
      #pragma unroll
      for (int fr = 0; fr < 2; ++fr) {
        #pragma unroll
        for (int i = 0; i < 4; ++i) {
          const int row = fr * 16 + lhi * 4 + i;
          const float x = hacc[fr][fc][i] + dbv;
          *(u16*)(hb + row * 512 + ((hc * 2) ^ ((row & 7) << 4))) = f2bf(gelu_f(x) * wbe);
        }
      }
    }

    if (e + 1 < E_) {
      const u16* dBn = dB + (size_t)(e + 1) * 32 * 16 * 512;
      #pragma unroll
      for (int p = 0; p < 4; ++p) {
        pb[p][0] = *(const s16x8*)(dBn + (size_t)p * 16 * 512);
        pb[p][1] = *(const s16x8*)(dBn + (size_t)p * 16 * 512 + 512);
      }
    }
    // single barrier/expert: publishes Hb[e&1]; up(e) reads it while gelu(e+1)
    // writes the OTHER buffer; up(e+1) gated by barrier(e+1).
    __syncthreads();

    // ---- UP: acc[32 x 128cols/wave] += Hb @ uw[e] ----
    s16x8 ua[2][2];
    #pragma unroll
    for (int fr = 0; fr < 2; ++fr)
      ua[0][fr] = *(const s16x8*)(hb + (l15 + fr * 16) * 512 + ((lhi * 16) ^ sw7));
    #pragma unroll
    for (int ks = 0; ks < 8; ++ks) {
      const int cur = ks & 1, nxt = cur ^ 1;
      if (ks < 7) {
        const int kb = (ks + 1) * 64;
        #pragma unroll
        for (int fr = 0; fr < 2; ++fr)
          ua[nxt][fr] = *(const s16x8*)(hb + (l15 + fr * 16) * 512 + ((kb + lhi * 16) ^ sw7));
        #pragma unroll
        for (int fc = 0; fc < 8; ++fc)
          ub[nxt][fc] = *(const s16x8*)(uBe + ((size_t)(ks + 1) * 64 + fc) * 512);
      }
      #pragma unroll
      for (int fc = 0; fc < 8; ++fc) {
        #pragma unroll
        for (int fr = 0; fr < 2; ++fr)
          acc[fr][fc] = MFMA_BF16(ua[cur][fr], ub[cur][fc], acc[fr][fc], 0, 0, 0);
      }
    }
  }

  // ---- epilogue: residual + bias + store ----
  const float* bias = biasws + b * D_;
  #pragma unroll
  for (int fc = 0; fc < 8; ++fc) {
    const int col = w * 128 + fc * 16 + l15;
    const float bv = bias[col];
    #pragma unroll
    for (int fr = 0; fr < 2; ++fr) {
      #pragma unroll
      for (int i = 0; i < 4; ++i) {
        const int row = fr * 16 + lhi * 4 + i;
        const size_t idx = (size_t)(r0 + row) * D_ + col;
        out[idx] = acc[fr][fc][i] + Ff32[idx] + bv;
      }
    }
  }
}

extern "C" void kernel_launch(void* const* d_in, const int* in_sizes, int n_in,
                              void* d_out, int out_size, void* d_ws, size_t ws_size,
                              hipStream_t stream) {
  const float* F  = (const float*)d_in[0];
  const float* X  = (const float*)d_in[1];
  const float* dw = (const float*)d_in[2];
  const float* db = (const float*)d_in[3];
  const float* uw = (const float*)d_in[4];
  const float* ub = (const float*)d_in[5];
  const float* cw = (const float*)d_in[6];
  const float* cb = (const float*)d_in[7];
  const float* sw = (const float*)d_in[8];
  const float* sb = (const float*)d_in[9];
  float* out = (float*)d_out;

  char* ws = (char*)d_ws;
  float* fsum  = (float*)ws;                 // B*D
  float* xsum  = fsum + B_ * D_;             // B*SD
  float* flatw = xsum + B_ * SD_;            // B*E
  float* biasws = flatw + B_ * E_;           // B*D
  size_t off = (size_t)(B_ * D_ + B_ * SD_ + B_ * E_ + B_ * D_) * 4;
  off = (off + 255) & ~(size_t)255;
  u16* dwF = (u16*)(ws + off); off += (size_t)E_ * H_ * D_ * 2;
  u16* uwF = (u16*)(ws + off); off += (size_t)E_ * D_ * H_ * 2;
  const size_t need_lean = off;
  u16* Fbf = (u16*)(ws + off); off += (size_t)B_ * S_ * D_ * 2;
  const size_t need_full = off;

  if (ws_size < need_lean) return;
  const bool lean = ws_size < need_full;

  hipMemsetAsync(d_ws, 0, (size_t)(B_ * D_ + B_ * SD_) * sizeof(float), stream);
  // fragmentize: dw [E][D=K][H=N] -> dwF ; uw [E][H=K][D=N] -> uwF
  k_frag<<<E_ * (H_ / 16) * (D_ / 128), 256, 0, stream>>>(dw, dwF, D_, H_);
  k_frag<<<E_ * (D_ / 16) * (H_ / 128), 256, 0, stream>>>(uw, uwF, H_, D_);
  if (!lean) {
    k_convpool<<<512, 256, 0, stream>>>(F, Fbf, fsum);
  } else {
    k_poolF<<<512, 256, 0, stream>>>(F, fsum);
  }
  k_xpool<<<B_, 256, 0, stream>>>(X, xsum);
  k_router<<<1, 256, 0, stream>>>(fsum, xsum, cw, cb, sw, sb, ub, flatw, biasws,
                                  out + (size_t)B_ * S_ * D_);
  if (!lean) {
    k_moe<0><<<1024, 512, 0, stream>>>(Fbf, F, dwF, uwF, db, flatw, biasws, out);
  } else {
    k_moe<1><<<1024, 512, 0, stream>>>(nullptr, F, dwF, uwF, db, flatw, biasws, out);
  }
}